// Round 1
// baseline (597.893 us; speedup 1.0000x reference)
//
#include <hip/hip_runtime.h>
#include <hip/hip_fp16.h>
#include <stdint.h>

#define NEG_ (-1e9f)

typedef _Float16 f16x8 __attribute__((ext_vector_type(8)));
typedef float    f32x4 __attribute__((ext_vector_type(4)));

__device__ __forceinline__ float fast_tanh(float x) {
  // tanh(x) = (e^{2x}-1)/(e^{2x}+1); v_exp+v_rcp, ~1e-6 abs error, no overflow for |x|<44
  float e = __expf(2.0f * x);
  return (e - 1.0f) * __builtin_amdgcn_rcpf(e + 1.0f);
}

// ---------------------------------------------------------------------------
// K0: repack W [512 o][512 h] fp32 -> f16 laid out as the exact MFMA A-fragment
// stream K1 consumes: segment(oc,w,ks,io) = ((oc*4+w)*32 + ks*2 + io), 1KB each,
// lane i holds W[o = oc*128+w*32+io*16+(i&15)][k = ks*32+(i>>4)*8 .. +8)].
// ---------------------------------------------------------------------------
__global__ __launch_bounds__(256) void k0_cvt_w(const float* __restrict__ W,
                                                __half* __restrict__ Wws) {
  int g = blockIdx.x * 256 + threadIdx.x;   // 0..32767, one 16B chunk each
  int lane = g & 63;
  int seg  = g >> 6;                        // 0..511
  int io = seg & 1, ks = (seg >> 1) & 15, w = (seg >> 5) & 3, c = seg >> 7;
  int o = c * 128 + w * 32 + io * 16 + (lane & 15);
  int k = ks * 32 + (lane >> 4) * 8;
  const float2* src = (const float2*)(W + (size_t)o * 512 + k);
  __half2 h[4];
#pragma unroll
  for (int j = 0; j < 4; ++j) { float2 f = src[j]; h[j] = __floats2half2_rn(f.x, f.y); }
  uint4 u;
  u.x = *(uint32_t*)&h[0]; u.y = *(uint32_t*)&h[1];
  u.z = *(uint32_t*)&h[2]; u.w = *(uint32_t*)&h[3];
  *(uint4*)(Wws + (size_t)seg * 512 + (size_t)lane * 8) = u;
}

// ---------------------------------------------------------------------------
// K1: scores[m] = mask[m] ? v . tanh(W x_m + b) : -1e9   for 64 rows per block.
// X tile staged once to LDS as swizzled f16 (64KB -> 2 blocks/CU). A-operand
// (W) streamed straight from L2 in fragment order. 4 waves x (32o x 64s),
// o-chunks x4, K = 16 stages of 32.
// ---------------------------------------------------------------------------
__global__ __launch_bounds__(256, 2) void k1_scores(
    const float* __restrict__ enc, const int* __restrict__ msk,
    const float* __restrict__ bias, const float* __restrict__ ctx,
    const __half* __restrict__ Wws, float* __restrict__ scores) {
  __shared__ __align__(16) __half Xl[64 * 512];  // 64 KB, reused for final reduction

  const int t = threadIdx.x;
  const int w = t >> 6;
  const int lane = t & 63;
  const int quad = lane >> 4;
  const int l15 = lane & 15;
  const size_t mtile = blockIdx.x;

  // ---- stage X tile [64 s][512 h] fp32 -> f16, XOR-swizzled 16B chunks ----
  {
    const float4* Xg = (const float4*)(enc + mtile * (size_t)(64 * 512));
#pragma unroll 8
    for (int j = 0; j < 32; ++j) {
      int f = j * 256 + t;            // float4 index 0..8191 (perfectly coalesced)
      int s = f >> 7, pos = f & 127;  // pos = float4 within row
      float4 x = Xg[f];
      __half2 h0 = __floats2half2_rn(x.x, x.y);
      __half2 h1 = __floats2half2_rn(x.z, x.w);
      // phys(s,h) = s*512 + (((h>>3) ^ (s&7))<<3) + (h&7); here h = pos*4
      int phys = s * 512 + ((((pos >> 1) ^ (s & 7)) << 3) | ((pos & 1) << 2));
      uint2 u; u.x = *(uint32_t*)&h0; u.y = *(uint32_t*)&h1;
      *(uint2*)&Xl[phys] = u;
    }
  }
  __syncthreads();

  float sacc[4] = {0.f, 0.f, 0.f, 0.f};

  for (int oc = 0; oc < 4; ++oc) {
    const __half* wseg = Wws + ((size_t)(oc * 4 + w) * 32) * 512 + (size_t)lane * 8;
    f32x4 acc[2][4];
#pragma unroll
    for (int io = 0; io < 2; ++io)
#pragma unroll
      for (int is = 0; is < 4; ++is) acc[io][is] = (f32x4){0.f, 0.f, 0.f, 0.f};

#pragma unroll
    for (int ks = 0; ks < 16; ++ks) {
      // A fragments: linear 1KB/wave reads from L2-resident repacked W
      f16x8 a0 = *(const f16x8*)(wseg + ks * 1024);
      f16x8 a1 = *(const f16x8*)(wseg + ks * 1024 + 512);
      int cb = ks * 4 + quad;  // 16B-chunk index of this lane's k-run
#pragma unroll
      for (int is = 0; is < 4; ++is) {
        int s = is * 16 + l15;
        const f16x8 bf = *(const f16x8*)&Xl[s * 512 + ((cb ^ (s & 7)) << 3)];
        acc[0][is] = __builtin_amdgcn_mfma_f32_16x16x32_f16(a0, bf, acc[0][is], 0, 0, 0);
        acc[1][is] = __builtin_amdgcn_mfma_f32_16x16x32_f16(a1, bf, acc[1][is], 0, 0, 0);
      }
    }

    // epilogue: fold tanh(acc + b) * v into per-row partial scores
    float ps[4] = {0.f, 0.f, 0.f, 0.f};
#pragma unroll
    for (int io = 0; io < 2; ++io) {
      int ob = oc * 128 + w * 32 + io * 16 + quad * 4;  // C row m = quad*4 + reg
      float4 b4 = *(const float4*)(bias + ob);
      float4 v4 = *(const float4*)(ctx + ob);
#pragma unroll
      for (int is = 0; is < 4; ++is) {
        const f32x4 a = acc[io][is];
        ps[is] += fast_tanh(a[0] + b4.x) * v4.x + fast_tanh(a[1] + b4.y) * v4.y +
                  fast_tanh(a[2] + b4.z) * v4.z + fast_tanh(a[3] + b4.w) * v4.w;
      }
    }
#pragma unroll
    for (int is = 0; is < 4; ++is) {   // sum over the 32 o's of this wave tile
      float p = ps[is];
      p += __shfl_xor(p, 16, 64);
      p += __shfl_xor(p, 32, 64);
      sacc[is] += p;
    }
  }

  // cross-wave reduction (X tile is dead now -> reuse its LDS)
  __syncthreads();
  float* sred = (float*)&Xl[0];
  if (lane < 16) {
#pragma unroll
    for (int is = 0; is < 4; ++is) sred[w * 64 + is * 16 + lane] = sacc[is];
  }
  __syncthreads();
  if (t < 64) {
    float sc = sred[t] + sred[64 + t] + sred[128 + t] + sred[192 + t];
    size_t row = mtile * 64 + t;
    scores[row] = msk[row] ? sc : NEG_;
  }
}

// ---------------------------------------------------------------------------
// K2: in-place masked softmax over S=2048 per batch row (scores -> attn)
// ---------------------------------------------------------------------------
__global__ __launch_bounds__(256) void k2_softmax(float* __restrict__ attn) {
  const int b = blockIdx.x, t = threadIdx.x;
  float* row = attn + (size_t)b * 2048;
  float v[8];
  float mx = -3.4e38f;
#pragma unroll
  for (int i = 0; i < 8; ++i) { v[i] = row[t + 256 * i]; mx = fmaxf(mx, v[i]); }
#pragma unroll
  for (int off = 32; off >= 1; off >>= 1) mx = fmaxf(mx, __shfl_xor(mx, off, 64));
  __shared__ float r1[4], r2[4];
  int w = t >> 6, lane = t & 63;
  if (lane == 0) r1[w] = mx;
  __syncthreads();
  mx = fmaxf(fmaxf(r1[0], r1[1]), fmaxf(r1[2], r1[3]));
  float sum = 0.f;
#pragma unroll
  for (int i = 0; i < 8; ++i) { v[i] = __expf(v[i] - mx); sum += v[i]; }
#pragma unroll
  for (int off = 32; off >= 1; off >>= 1) sum += __shfl_xor(sum, off, 64);
  if (lane == 0) r2[w] = sum;
  __syncthreads();
  sum = r2[0] + r2[1] + r2[2] + r2[3];
  float inv = 1.0f / sum;
#pragma unroll
  for (int i = 0; i < 8; ++i) row[t + 256 * i] = v[i] * inv;
}

// ---------------------------------------------------------------------------
// K3: out[b,h] = sum_s attn[b,s] * x[b,s,h].  512 blocks (b x 8 s-chunks),
// fp32 atomics into zeroed out0. Pure HBM stream of X.
// ---------------------------------------------------------------------------
__global__ __launch_bounds__(256) void k3_wsum(const float* __restrict__ enc,
                                               const float* __restrict__ attn,
                                               float* __restrict__ out0) {
  const int bb = blockIdx.x >> 3, sc = blockIdx.x & 7, t = threadIdx.x;
  __shared__ float a_s[256];
  a_s[t] = attn[(size_t)bb * 2048 + sc * 256 + t];
  __syncthreads();
  const float2* x2 = (const float2*)(enc + ((size_t)bb * 2048 + (size_t)sc * 256) * 512) + t;
  float2 acc0 = {0.f, 0.f}, acc1 = {0.f, 0.f};
#pragma unroll 4
  for (int s = 0; s < 256; s += 2) {
    float a0 = a_s[s], a1 = a_s[s + 1];
    float2 xv0 = x2[(size_t)s * 256];
    float2 xv1 = x2[(size_t)(s + 1) * 256];
    acc0.x = fmaf(a0, xv0.x, acc0.x); acc0.y = fmaf(a0, xv0.y, acc0.y);
    acc1.x = fmaf(a1, xv1.x, acc1.x); acc1.y = fmaf(a1, xv1.y, acc1.y);
  }
  atomicAdd(&out0[bb * 512 + 2 * t],     acc0.x + acc1.x);
  atomicAdd(&out0[bb * 512 + 2 * t + 1], acc0.y + acc1.y);
}

// ---------------------------------------------------------------------------
extern "C" void kernel_launch(void* const* d_in, const int* in_sizes, int n_in,
                              void* d_out, int out_size, void* d_ws, size_t ws_size,
                              hipStream_t stream) {
  (void)in_sizes; (void)n_in; (void)out_size; (void)ws_size;
  const float* enc  = (const float*)d_in[0];  // [64,2048,512] fp32
  const int*   msk  = (const int*)d_in[1];    // [64,2048] bool->int32
  const float* W    = (const float*)d_in[2];  // [512,512] fp32
  const float* bias = (const float*)d_in[3];  // [512] fp32
  const float* ctx  = (const float*)d_in[4];  // [512] fp32
  float* out0 = (float*)d_out;                // [64,512] weighted output
  float* attn = out0 + 64 * 512;              // [64,2048] scores -> attn (in place)
  __half* Wws = (__half*)d_ws;                // 512 KB repacked W

  hipMemsetAsync(out0, 0, 64 * 512 * sizeof(float), stream);
  k0_cvt_w<<<128, 256, 0, stream>>>(W, Wws);
  k1_scores<<<2048, 256, 0, stream>>>(enc, msk, bias, ctx, Wws, attn);
  k2_softmax<<<64, 256, 0, stream>>>(attn);
  k3_wsum<<<512, 256, 0, stream>>>(enc, attn, out0);
}

// Round 2
// 532.139 us; speedup vs baseline: 1.1236x; 1.1236x over previous
//
#include <hip/hip_runtime.h>
#include <hip/hip_fp16.h>
#include <stdint.h>

#define NEG_ (-1e9f)

typedef _Float16 f16x8 __attribute__((ext_vector_type(8)));
typedef float    f32x4 __attribute__((ext_vector_type(4)));

__device__ __forceinline__ float fast_tanh(float x) {
  float e = __expf(2.0f * x);
  return (e - 1.0f) * __builtin_amdgcn_rcpf(e + 1.0f);
}

// ---------------------------------------------------------------------------
// K0: repack W [512 o][512 h] fp32 -> f16 in MFMA A-fragment stream order.
// seg = oc*256 + w*64 + ks*4 + io  (1KB each);
// lane i holds W[o = oc*256+w*64+io*16+(i&15)][k = ks*32+(i>>4)*8 .. +8)
// ---------------------------------------------------------------------------
__global__ __launch_bounds__(256) void k0_cvt_w(const float* __restrict__ W,
                                                __half* __restrict__ Wws) {
  int g = blockIdx.x * 256 + threadIdx.x;   // 0..32767, one 16B chunk each
  int lane = g & 63;
  int seg  = g >> 6;                        // 0..511
  int io = seg & 3, ks = (seg >> 2) & 15, w = (seg >> 6) & 3, oc = seg >> 8;
  int o = oc * 256 + w * 64 + io * 16 + (lane & 15);
  int k = ks * 32 + (lane >> 4) * 8;
  const float2* src = (const float2*)(W + (size_t)o * 512 + k);
  __half2 h[4];
#pragma unroll
  for (int j = 0; j < 4; ++j) { float2 f = src[j]; h[j] = __floats2half2_rn(f.x, f.y); }
  uint4 u;
  u.x = *(uint32_t*)&h[0]; u.y = *(uint32_t*)&h[1];
  u.z = *(uint32_t*)&h[2]; u.w = *(uint32_t*)&h[3];
  *(uint4*)(Wws + (size_t)seg * 512 + (size_t)lane * 8) = u;
}

// ---------------------------------------------------------------------------
// K1: scores[m] = mask[m] ? v . tanh(W x_m + b) : -1e9 for 64 rows per block.
// X tile staged once to LDS (swizzled f16, ds_write_b128). 4 waves x (64o x
// 64s), 2 o-chunks, K = 16 stages of 32. A operand software-pipelined from
// L2 with depth-2 prefetch (3-slot register ring).
// ---------------------------------------------------------------------------
__global__ __launch_bounds__(256, 2) void k1_scores(
    const float* __restrict__ enc, const int* __restrict__ msk,
    const float* __restrict__ bias, const float* __restrict__ ctx,
    const __half* __restrict__ Wws, float* __restrict__ scores) {
  __shared__ __align__(16) __half Xl[64 * 512];  // 64 KB

  const int t = threadIdx.x;
  const int w = t >> 6;
  const int lane = t & 63;
  const int quad = lane >> 4;
  const int l15 = lane & 15;
  const size_t mtile = blockIdx.x;

  // ---- stage X tile [64 s][512 h] fp32 -> f16, XOR-swizzled 16B chunks ----
  {
    const float4* Xg = (const float4*)(enc + mtile * (size_t)(64 * 512));
#pragma unroll
    for (int j = 0; j < 16; ++j) {
      int g = j * 256 + t;        // f16 16B-chunk index 0..4095
      int s = g >> 6, c = g & 63;
      float4 x0 = Xg[s * 128 + 2 * c];
      float4 x1 = Xg[s * 128 + 2 * c + 1];
      __half2 h0 = __floats2half2_rn(x0.x, x0.y);
      __half2 h1 = __floats2half2_rn(x0.z, x0.w);
      __half2 h2 = __floats2half2_rn(x1.x, x1.y);
      __half2 h3 = __floats2half2_rn(x1.z, x1.w);
      uint4 u;
      u.x = *(uint32_t*)&h0; u.y = *(uint32_t*)&h1;
      u.z = *(uint32_t*)&h2; u.w = *(uint32_t*)&h3;
      int pc = c ^ (s & 7);     // phys chunk: bijective per wave -> conflict-free
      *(uint4*)&Xl[s * 512 + pc * 8] = u;
    }
  }
  __syncthreads();

  float sacc[4] = {0.f, 0.f, 0.f, 0.f};

  // A-fragment register ring, depth-2 prefetch
  f16x8 abuf[3][4];
  auto aload = [&](int slot, int iter) {
    int oc = iter >> 4, ks = iter & 15;
    const f16x8* sp = (const f16x8*)(Wws +
        ((size_t)((oc * 4 + w) * 64 + ks * 4) * 512) + (size_t)lane * 8);
#pragma unroll
    for (int io = 0; io < 4; ++io) abuf[slot][io] = sp[io * 64];
  };
  aload(0, 0);
  aload(1, 1);

#pragma unroll
  for (int oc = 0; oc < 2; ++oc) {
    f32x4 acc[4][4];
#pragma unroll
    for (int io = 0; io < 4; ++io)
#pragma unroll
      for (int is = 0; is < 4; ++is) acc[io][is] = (f32x4){0.f, 0.f, 0.f, 0.f};

#pragma unroll
    for (int ks = 0; ks < 16; ++ks) {
      const int iter = oc * 16 + ks;
      if (iter + 2 < 32) aload((iter + 2) % 3, iter + 2);  // prefetch ahead
      const f16x8* acur = abuf[iter % 3];
#pragma unroll
      for (int is = 0; is < 4; ++is) {
        int s = is * 16 + l15;
        const f16x8 bf = *(const f16x8*)&Xl[s * 512 + (((ks * 4 + quad) ^ (s & 7)) << 3)];
#pragma unroll
        for (int io = 0; io < 4; ++io)
          acc[io][is] = __builtin_amdgcn_mfma_f32_16x16x32_f16(acur[io], bf, acc[io][is], 0, 0, 0);
      }
    }

    // epilogue: fold tanh(acc + b) * v into per-row partial scores
    float ps[4] = {0.f, 0.f, 0.f, 0.f};
#pragma unroll
    for (int io = 0; io < 4; ++io) {
      int ob = oc * 256 + w * 64 + io * 16 + quad * 4;  // C row m = quad*4 + reg
      float4 b4 = *(const float4*)(bias + ob);
      float4 v4 = *(const float4*)(ctx + ob);
#pragma unroll
      for (int is = 0; is < 4; ++is) {
        const f32x4 a = acc[io][is];
        ps[is] += fast_tanh(a[0] + b4.x) * v4.x + fast_tanh(a[1] + b4.y) * v4.y +
                  fast_tanh(a[2] + b4.z) * v4.z + fast_tanh(a[3] + b4.w) * v4.w;
      }
    }
#pragma unroll
    for (int is = 0; is < 4; ++is) {   // sum over this wave's 64 o's
      float p = ps[is];
      p += __shfl_xor(p, 16, 64);
      p += __shfl_xor(p, 32, 64);
      sacc[is] += p;
    }
  }

  // cross-wave reduction (X tile is dead now -> reuse its LDS)
  __syncthreads();
  float* sred = (float*)&Xl[0];
  if (lane < 16) {
#pragma unroll
    for (int is = 0; is < 4; ++is) sred[w * 64 + is * 16 + lane] = sacc[is];
  }
  __syncthreads();
  if (t < 64) {
    float sc = sred[t] + sred[64 + t] + sred[128 + t] + sred[192 + t];
    size_t row = mtile * 64 + t;
    scores[row] = msk[row] ? sc : NEG_;
  }
}

// ---------------------------------------------------------------------------
// K2: in-place masked softmax over S=2048 per batch row (scores -> attn)
// ---------------------------------------------------------------------------
__global__ __launch_bounds__(256) void k2_softmax(float* __restrict__ attn) {
  const int b = blockIdx.x, t = threadIdx.x;
  float* row = attn + (size_t)b * 2048;
  float v[8];
  float mx = -3.4e38f;
#pragma unroll
  for (int i = 0; i < 8; ++i) { v[i] = row[t + 256 * i]; mx = fmaxf(mx, v[i]); }
#pragma unroll
  for (int off = 32; off >= 1; off >>= 1) mx = fmaxf(mx, __shfl_xor(mx, off, 64));
  __shared__ float r1[4], r2[4];
  int w = t >> 6, lane = t & 63;
  if (lane == 0) r1[w] = mx;
  __syncthreads();
  mx = fmaxf(fmaxf(r1[0], r1[1]), fmaxf(r1[2], r1[3]));
  float sum = 0.f;
#pragma unroll
  for (int i = 0; i < 8; ++i) { v[i] = __expf(v[i] - mx); sum += v[i]; }
#pragma unroll
  for (int off = 32; off >= 1; off >>= 1) sum += __shfl_xor(sum, off, 64);
  if (lane == 0) r2[w] = sum;
  __syncthreads();
  sum = r2[0] + r2[1] + r2[2] + r2[3];
  float inv = 1.0f / sum;
#pragma unroll
  for (int i = 0; i < 8; ++i) row[t + 256 * i] = v[i] * inv;
}

// ---------------------------------------------------------------------------
// K3: out[b,h] = sum_s attn[b,s] * x[b,s,h].  2048 blocks (b x 32 s-chunks of
// 64 rows), 8 blocks/CU, float4 streams, fp32 atomics into zeroed out0.
// ---------------------------------------------------------------------------
__global__ __launch_bounds__(256) void k3_wsum(const float* __restrict__ enc,
                                               const float* __restrict__ attn,
                                               float* __restrict__ out0) {
  const int bb = blockIdx.x >> 5, sc = blockIdx.x & 31, t = threadIdx.x;
  const int r = t >> 7;        // 0/1: which row parity this thread covers
  const int c = t & 127;       // float4 column
  __shared__ float a_s[64];
  if (t < 64) a_s[t] = attn[(size_t)bb * 2048 + sc * 64 + t];
  __syncthreads();
  const float4* Xg = (const float4*)(enc + ((size_t)bb * 2048 + (size_t)sc * 64) * 512);
  float4 acc = {0.f, 0.f, 0.f, 0.f};
#pragma unroll 8
  for (int s = r; s < 64; s += 2) {
    float a = a_s[s];
    float4 x = Xg[(size_t)s * 128 + c];
    acc.x = fmaf(a, x.x, acc.x);
    acc.y = fmaf(a, x.y, acc.y);
    acc.z = fmaf(a, x.z, acc.z);
    acc.w = fmaf(a, x.w, acc.w);
  }
  float* op = out0 + (size_t)bb * 512 + c * 4;
  atomicAdd(op + 0, acc.x);
  atomicAdd(op + 1, acc.y);
  atomicAdd(op + 2, acc.z);
  atomicAdd(op + 3, acc.w);
}

// ---------------------------------------------------------------------------
extern "C" void kernel_launch(void* const* d_in, const int* in_sizes, int n_in,
                              void* d_out, int out_size, void* d_ws, size_t ws_size,
                              hipStream_t stream) {
  (void)in_sizes; (void)n_in; (void)out_size; (void)ws_size;
  const float* enc  = (const float*)d_in[0];  // [64,2048,512] fp32
  const int*   msk  = (const int*)d_in[1];    // [64,2048] bool->int32
  const float* W    = (const float*)d_in[2];  // [512,512] fp32
  const float* bias = (const float*)d_in[3];  // [512] fp32
  const float* ctx  = (const float*)d_in[4];  // [512] fp32
  float* out0 = (float*)d_out;                // [64,512] weighted output
  float* attn = out0 + 64 * 512;              // [64,2048] scores -> attn (in place)
  __half* Wws = (__half*)d_ws;                // 512 KB repacked W

  hipMemsetAsync(out0, 0, 64 * 512 * sizeof(float), stream);
  k0_cvt_w<<<128, 256, 0, stream>>>(W, Wws);
  k1_scores<<<2048, 256, 0, stream>>>(enc, msk, bias, ctx, Wws, attn);
  k2_softmax<<<64, 256, 0, stream>>>(attn);
  k3_wsum<<<2048, 256, 0, stream>>>(enc, attn, out0);
}